// Round 7
// baseline (131.956 us; speedup 1.0000x reference)
//
#include <hip/hip_runtime.h>

// DendralNeuron: out[b,d] = min( min_f(x[b,f]-Wmin[d,f]), min_f(Wmax[d,f]-x[b,f]) )
// R7: R6 structure (LDS, 1-wave blocks, 8x8 tile, ws-split, reduce) with
// instruction discipline. R6 post-mortem: 34.5us of VALU issue vs 10.5us
// ideal -> ~3x instr bloat. Suspects: (a) fsub v2f32 scalarizes (no v_pk_sub
// pattern; R3 "pk" change was neutral = never formed), (b) register pressure
// (need ~140 live, compiler allocated 84 -> LDS re-reads + movs).
// Fixes: inline-asm v_pk_add_f32 neg_lo/hi:[0,1] = guaranteed packed sub
// (4 pk + 4 v_min3 = 8 VALU per (r,c) f-quad = floor); xv[8] resident +
// nv/wv streamed per-c (small live set); cross-chunk register prefetch;
// launch_bounds(64,2) so the allocator has room (grid only needs 2 waves/SIMD).

constexpr int F_DIM = 784;
constexpr int BK = 8;
constexpr int NCHUNK = F_DIM / BK;   // 98
constexpr int BM = 32;
constexpr int BN = 128;
constexpr int LSTR = BK + 4;         // 12 floats: 48B rows, 16B-aligned, 2-way banks
constexpr int ZSPLIT = 16;

typedef float f4v __attribute__((ext_vector_type(4)));
typedef float f2v __attribute__((ext_vector_type(2)));

// Packed fp32 subtract: d = a - b via v_pk_add_f32 with src1 negation.
__device__ inline f2v pk_sub(f2v a, f2v b) {
  f2v d;
  asm("v_pk_add_f32 %0, %1, %2 neg_lo:[0,1] neg_hi:[0,1]"
      : "=v"(d) : "v"(a), "v"(b));
  return d;
}

__global__ __launch_bounds__(64, 2)
void dendral_main(const float* __restrict__ x,
                  const float* __restrict__ wmin,
                  const float* __restrict__ wmax,
                  float* __restrict__ dst,    // ws slices, or out when zsplit==1
                  int D, long long sliceN, int zsplit) {
  __shared__ float lx[BM * LSTR];     // 1.5 KB
  __shared__ float lwn[BN * LSTR];    // 6 KB
  __shared__ float lwx[BN * LSTR];    // 6 KB

  const int l  = threadIdx.x;         // 0..63, one wave
  const int tx = l & 15;              // d cols: tx + 16*c, c<8
  const int ty = l >> 4;              // b rows: ty + 4*r, r<8
  const int b0 = blockIdx.x * BM;
  const int d0 = blockIdx.y * BN;
  const int z  = blockIdx.z;
  const int c0 = (z * NCHUNK) / zsplit;
  const int c1 = ((z + 1) * NCHUNK) / zsplit;

  // Staging map per BK=8 chunk: x 32x8 = 64 float4 -> 1/lane;
  // W tiles 128x8 = 256 float4 each -> 4/lane.
  const int sr = l >> 1;              // 0..31
  const int sc = (l & 1) << 2;        // 0 or 4
  const float* xg = x + (size_t)(b0 + sr) * F_DIM + sc;
  const float* ng = wmin + (size_t)(d0 + sr) * F_DIM + sc;
  const float* wg = wmax + (size_t)(d0 + sr) * F_DIM + sc;
  float* lds_x = lx + sr * LSTR + sc;
  float* lds_n = lwn + sr * LSTR + sc;
  float* lds_w = lwx + sr * LSTR + sc;
  const size_t wrow_step = (size_t)32 * F_DIM;
  const int    lrow_step = 32 * LSTR;

  float acc[8][8];
#pragma unroll
  for (int r = 0; r < 8; ++r)
#pragma unroll
    for (int c = 0; c < 8; ++c) acc[r][c] = __builtin_inff();

  // Prefetch chunk c0 into registers.
  f4v gx = *(const f4v*)(xg + c0 * BK);
  f4v gn[4], gw[4];
#pragma unroll
  for (int i = 0; i < 4; ++i) {
    gn[i] = *(const f4v*)(ng + i * wrow_step + c0 * BK);
    gw[i] = *(const f4v*)(wg + i * wrow_step + c0 * BK);
  }

  for (int kc = c0; kc < c1; ++kc) {
    __syncthreads();                  // WAR: prior chunk's reads done (1 wave)
    *(f4v*)lds_x = gx;
#pragma unroll
    for (int i = 0; i < 4; ++i) {
      *(f4v*)(lds_n + i * lrow_step) = gn[i];
      *(f4v*)(lds_w + i * lrow_step) = gw[i];
    }
    if (kc + 1 < c1) {                // prefetch next chunk during compute
      const int fo = (kc + 1) * BK;
      gx = *(const f4v*)(xg + fo);
#pragma unroll
      for (int i = 0; i < 4; ++i) {
        gn[i] = *(const f4v*)(ng + i * wrow_step + fo);
        gw[i] = *(const f4v*)(wg + i * wrow_step + fo);
      }
    }
    __syncthreads();                  // RAW: LDS writes visible (1 wave)

#pragma unroll
    for (int f = 0; f < BK; f += 4) {
      f4v xv[8];
#pragma unroll
      for (int r = 0; r < 8; ++r)     // 4 distinct addrs/wave -> broadcast
        xv[r] = *(const f4v*)&lx[(ty + 4 * r) * LSTR + f];
#pragma unroll
      for (int c = 0; c < 8; ++c) {   // stream nv/wv: 8 live operand regs
        f4v nv = *(const f4v*)&lwn[(tx + 16 * c) * LSTR + f];
        f4v wv = *(const f4v*)&lwx[(tx + 16 * c) * LSTR + f];
#pragma unroll
        for (int r = 0; r < 8; ++r) {
          f2v a_lo = pk_sub(xv[r].xy, nv.xy);   // x - Wmin (packed)
          f2v a_hi = pk_sub(xv[r].zw, nv.zw);
          f2v b_lo = pk_sub(wv.xy, xv[r].xy);   // Wmax - x (packed)
          f2v b_hi = pk_sub(wv.zw, xv[r].zw);
          float m = acc[r][c];
          m = fminf(m, fminf(a_lo.x, a_lo.y));  // v_min3 x4
          m = fminf(m, fminf(a_hi.x, a_hi.y));
          m = fminf(m, fminf(b_lo.x, b_lo.y));
          m = fminf(m, fminf(b_hi.x, b_hi.y));
          acc[r][c] = m;
        }
      }
    }
  }

  float* o = dst + (size_t)z * sliceN;   // plain coalesced stores, no atomics
#pragma unroll
  for (int r = 0; r < 8; ++r)
#pragma unroll
    for (int c = 0; c < 8; ++c) {
      const int b = b0 + ty + 4 * r;
      const int d = d0 + tx + 16 * c;
      o[(size_t)b * D + d] = acc[r][c];
    }
}

__global__ __launch_bounds__(256, 4)
void dendral_reduce(const float* __restrict__ ws, float* __restrict__ out,
                    long long sliceN, int zsplit) {
  const long long i = (long long)blockIdx.x * 256 + threadIdx.x;  // float4 idx
  f4v m = ((const f4v*)ws)[i];
  for (int z = 1; z < zsplit; ++z) {
    f4v v = ((const f4v*)(ws + (size_t)z * sliceN))[i];
    m.x = fminf(m.x, v.x); m.y = fminf(m.y, v.y);
    m.z = fminf(m.z, v.z); m.w = fminf(m.w, v.w);
  }
  ((f4v*)out)[i] = m;
}

extern "C" void kernel_launch(void* const* d_in, const int* in_sizes, int n_in,
                              void* d_out, int out_size, void* d_ws, size_t ws_size,
                              hipStream_t stream) {
  const float* x    = (const float*)d_in[0];
  const float* wmin = (const float*)d_in[1];
  const float* wmax = (const float*)d_in[2];
  float* out = (float*)d_out;
  const int B = in_sizes[0] / F_DIM;  // 1024
  const int D = in_sizes[1] / F_DIM;  // 512
  const long long sliceN = (long long)B * D;       // 524288

  // zsplit depends only on ws_size -> identical work every call (graph-safe).
  const int zsplit = (ws_size >= (size_t)ZSPLIT * sliceN * sizeof(float))
                         ? ZSPLIT : 1;
  float* dst = (zsplit > 1) ? (float*)d_ws : out;

  dim3 grid(B / BM, D / BN, zsplit);  // 32 x 4 x 16 = 2048 wave-blocks
  dendral_main<<<grid, 64, 0, stream>>>(x, wmin, wmax, dst, D, sliceN, zsplit);

  if (zsplit > 1) {
    dendral_reduce<<<(int)(sliceN / (256 * 4)), 256, 0, stream>>>(
        (const float*)d_ws, out, sliceN, zsplit);
  }
  (void)n_in; (void)out_size;
}

// Round 8
// 100.680 us; speedup vs baseline: 1.3106x; 1.3106x over previous
//
#include <hip/hip_runtime.h>

// DendralNeuron: out[b,d] = min( min_f(x[b,f]-Wmin[d,f]), min_f(Wmax[d,f]-x[b,f]) )
// R8: R6 structure, occupancy-shaped. Evidence: R6 (8x8 tile, balanced VALU
// ~15.7us / DS ~14us pipes) measured 46us with only 2 waves/SIMD resident ->
// stall-bound, not pipe-bound. R7's inline-asm pk_sub regressed (+35% instrs
// of register-shuffle movs) -> reverted; scalar subs + v_min3 is best codegen.
// Shape: 32x64 tile, TM=8 x TN=4 (acc 32 regs), BK=8, LDS 7.5KB, Z=16 ->
// 4096 one-wave blocks = 16 blocks/CU = 4 waves/SIMD (launch_bounds(64,4),
// live-set ~104 regs <= 128 cap). Inner: xv[8] upfront, nv/wv streamed per-c.
// Split-K partials to ws + reduce kernel (no atomics - R4's 121MB RMW lesson).

constexpr int F_DIM = 784;
constexpr int BK = 8;
constexpr int NCHUNK = F_DIM / BK;   // 98
constexpr int BM = 32;
constexpr int BN = 64;
constexpr int LSTR = BK + 4;         // 12 floats: 48B rows, 16B-aligned, 2-way banks
constexpr int ZSPLIT = 16;           // slices of 6-7 chunks

typedef float f4v __attribute__((ext_vector_type(4)));

__global__ __launch_bounds__(64, 4)
void dendral_main(const float* __restrict__ x,
                  const float* __restrict__ wmin,
                  const float* __restrict__ wmax,
                  float* __restrict__ dst,    // ws slices, or out when zsplit==1
                  int D, long long sliceN, int zsplit) {
  __shared__ float lx[BM * LSTR];     // 1.5 KB
  __shared__ float lwn[BN * LSTR];    // 3 KB
  __shared__ float lwx[BN * LSTR];    // 3 KB

  const int l  = threadIdx.x;         // 0..63, one wave
  const int tx = l & 15;              // d cols: tx + 16*c, c<4
  const int ty = l >> 4;              // b rows: ty + 4*r, r<8
  const int b0 = blockIdx.x * BM;
  const int d0 = blockIdx.y * BN;
  const int z  = blockIdx.z;
  const int c0 = (z * NCHUNK) / zsplit;
  const int c1 = ((z + 1) * NCHUNK) / zsplit;

  // Staging per BK=8 chunk: x 32x8 = 64 f4 -> 1/lane; W 64x8 = 128 f4 each
  // -> 2/lane (rows wr, wr+32).
  const int sr = l >> 1;              // 0..31
  const int sc = (l & 1) << 2;        // 0 or 4
  const float* xg = x + (size_t)(b0 + sr) * F_DIM + sc;
  const float* ng = wmin + (size_t)(d0 + sr) * F_DIM + sc;
  const float* wg = wmax + (size_t)(d0 + sr) * F_DIM + sc;
  float* lds_x = lx + sr * LSTR + sc;
  float* lds_n = lwn + sr * LSTR + sc;
  float* lds_w = lwx + sr * LSTR + sc;
  const size_t wrow_step = (size_t)32 * F_DIM;
  const int    lrow_step = 32 * LSTR;

  float acc[8][4];
#pragma unroll
  for (int r = 0; r < 8; ++r)
#pragma unroll
    for (int c = 0; c < 4; ++c) acc[r][c] = __builtin_inff();

  // Prefetch chunk c0 into registers (5 float4 = 20 VGPRs).
  f4v gx = *(const f4v*)(xg + c0 * BK);
  f4v gn0 = *(const f4v*)(ng + c0 * BK);
  f4v gn1 = *(const f4v*)(ng + wrow_step + c0 * BK);
  f4v gw0 = *(const f4v*)(wg + c0 * BK);
  f4v gw1 = *(const f4v*)(wg + wrow_step + c0 * BK);

  for (int kc = c0; kc < c1; ++kc) {
    __syncthreads();                  // WAR: prior chunk reads done (1 wave, ~free)
    *(f4v*)lds_x = gx;
    *(f4v*)lds_n = gn0;
    *(f4v*)(lds_n + lrow_step) = gn1;
    *(f4v*)lds_w = gw0;
    *(f4v*)(lds_w + lrow_step) = gw1;
    if (kc + 1 < c1) {                // prefetch next chunk during compute
      const int fo = (kc + 1) * BK;
      gx  = *(const f4v*)(xg + fo);
      gn0 = *(const f4v*)(ng + fo);
      gn1 = *(const f4v*)(ng + wrow_step + fo);
      gw0 = *(const f4v*)(wg + fo);
      gw1 = *(const f4v*)(wg + wrow_step + fo);
    }
    __syncthreads();                  // RAW: LDS writes visible (1 wave, ~free)

#pragma unroll
    for (int f = 0; f < BK; f += 4) {
      f4v xv[8];
#pragma unroll
      for (int r = 0; r < 8; ++r)     // 4 distinct addrs/wave -> broadcast
        xv[r] = *(const f4v*)&lx[(ty + 4 * r) * LSTR + f];
#pragma unroll
      for (int c = 0; c < 4; ++c) {   // stream nv/wv: 8 live operand regs
        f4v nv = *(const f4v*)&lwn[(tx + 16 * c) * LSTR + f];
        f4v wv = *(const f4v*)&lwx[(tx + 16 * c) * LSTR + f];
#pragma unroll
        for (int r = 0; r < 8; ++r) {
          float a0 = xv[r].x - nv.x, a1 = xv[r].y - nv.y;   // x - Wmin
          float a2 = xv[r].z - nv.z, a3 = xv[r].w - nv.w;
          float b0f = wv.x - xv[r].x, b1f = wv.y - xv[r].y; // Wmax - x
          float b2f = wv.z - xv[r].z, b3f = wv.w - xv[r].w;
          float m = acc[r][c];
          m = fminf(m, fminf(a0, a1));   // v_min3 x4
          m = fminf(m, fminf(a2, a3));
          m = fminf(m, fminf(b0f, b1f));
          m = fminf(m, fminf(b2f, b3f));
          acc[r][c] = m;
        }
      }
    }
  }

  float* o = dst + (size_t)z * sliceN;   // plain coalesced stores, no atomics
#pragma unroll
  for (int r = 0; r < 8; ++r)
#pragma unroll
    for (int c = 0; c < 4; ++c) {
      const int b = b0 + ty + 4 * r;
      const int d = d0 + tx + 16 * c;
      o[(size_t)b * D + d] = acc[r][c];
    }
}

__global__ __launch_bounds__(256, 4)
void dendral_reduce(const float* __restrict__ ws, float* __restrict__ out,
                    long long sliceN, int zsplit) {
  const long long i = (long long)blockIdx.x * 256 + threadIdx.x;  // float4 idx
  f4v m = ((const f4v*)ws)[i];
  for (int z = 1; z < zsplit; ++z) {
    f4v v = ((const f4v*)(ws + (size_t)z * sliceN))[i];
    m.x = fminf(m.x, v.x); m.y = fminf(m.y, v.y);
    m.z = fminf(m.z, v.z); m.w = fminf(m.w, v.w);
  }
  ((f4v*)out)[i] = m;
}

extern "C" void kernel_launch(void* const* d_in, const int* in_sizes, int n_in,
                              void* d_out, int out_size, void* d_ws, size_t ws_size,
                              hipStream_t stream) {
  const float* x    = (const float*)d_in[0];
  const float* wmin = (const float*)d_in[1];
  const float* wmax = (const float*)d_in[2];
  float* out = (float*)d_out;
  const int B = in_sizes[0] / F_DIM;  // 1024
  const int D = in_sizes[1] / F_DIM;  // 512
  const long long sliceN = (long long)B * D;       // 524288

  // zsplit depends only on ws_size -> identical work every call (graph-safe).
  const int zsplit = (ws_size >= (size_t)ZSPLIT * sliceN * sizeof(float))
                         ? ZSPLIT : 1;
  float* dst = (zsplit > 1) ? (float*)d_ws : out;

  dim3 grid(B / BM, D / BN, zsplit);  // 32 x 8 x 16 = 4096 one-wave blocks
  dendral_main<<<grid, 64, 0, stream>>>(x, wmin, wmax, dst, D, sliceN, zsplit);

  if (zsplit > 1) {
    dendral_reduce<<<(int)(sliceN / (256 * 4)), 256, 0, stream>>>(
        (const float*)d_ws, out, sliceN, zsplit);
  }
  (void)n_in; (void)out_size;
}